// Round 9
// baseline (189.947 us; speedup 1.0000x reference)
//
#include <hip/hip_runtime.h>
#include <stdint.h>
#include <math.h>

#define D_MODEL 1024
#define NUM_HEADS 16
#define D_K 64
#define SEQ 2048
#define BATCH 2
#define SIM_THRESH 0.7f

#define TS 64          // block tile (square)
#define BK 32          // K chunk per barrier
#define NIT (D_MODEL / BK)   // 32

#define NROWS (BATCH * SEQ)                       // 4096
#define VP_BLOCKS ((NROWS / TS) * (D_MODEL / TS)) // 64*16 = 1024
#define SIM_ROWB (SEQ / TS)                       // 32
#define SIM_TRI (SIM_ROWB * (SIM_ROWB + 1) / 2)   // 528
#define SIM_BLOCKS (SIM_TRI * BATCH)              // 1056
#define GRID (VP_BLOCKS + SIM_BLOCKS)             // 2080

typedef __attribute__((ext_vector_type(8))) short bf16x8;
typedef __attribute__((ext_vector_type(4))) float f32x4;

static __device__ __forceinline__ unsigned short f2bf(float f) {
    unsigned int u = __float_as_uint(f);
    unsigned int r = (u + 0x7FFF + ((u >> 16) & 1)) >> 16;   // RNE
    return (unsigned short)r;
}
static __device__ __forceinline__ float bf2f(unsigned short u) {
    return __uint_as_float(((unsigned int)u) << 16);
}
// float -> OCP e4m3fn (values here are small; handles normals+subnormals, ~RNE)
static __device__ __forceinline__ unsigned char f2e4m3(float x) {
    unsigned int u = __float_as_uint(x);
    unsigned char s = (unsigned char)((u >> 24) & 0x80);
    int e = (int)((u >> 23) & 0xFF) - 127;
    unsigned int m = u & 0x7FFFFF;
    if (e >= -6) {
        unsigned int keep = m >> 20;
        unsigned int rem = m & 0xFFFFF;
        keep += (rem > 0x80000u) || (rem == 0x80000u && (keep & 1));
        if (keep == 8) { keep = 0; ++e; }
        if (e > 8) return (unsigned char)(s | 0x7E);   // clamp (unreachable here)
        return (unsigned char)(s | ((e + 7) << 3) | keep);
    }
    float q = fabsf(x) * 512.0f;          // subnormal: quantum 2^-9
    int t = (int)(q + 0.5f);
    if (t >= 8) return (unsigned char)(s | 0x08);
    return (unsigned char)(s | t);
}

// ---------- L1: normalize x rows -> bf16 + fp8 (+norms, zero cnt); cast Wv -> bf16 ----------
__global__ __launch_bounds__(256) void k_prep(const float* __restrict__ x,
                                              const float* __restrict__ Wv,
                                              unsigned short* __restrict__ xn,
                                              unsigned char* __restrict__ xn8,
                                              unsigned short* __restrict__ Wvb,
                                              float* __restrict__ norms,
                                              int* __restrict__ cnt) {
    int bid = blockIdx.x, tid = threadIdx.x;
    int lane = tid & 63, wv = tid >> 6;
    if (bid < NROWS / 4) {
        int row = bid * 4 + wv;
        const float4* xr = (const float4*)(x + (size_t)row * D_MODEL);
        float4 vv[4];
        float ss = 0.f;
#pragma unroll
        for (int i = 0; i < 4; ++i) {
            vv[i] = xr[lane + i * 64];
            ss += vv[i].x * vv[i].x + vv[i].y * vv[i].y + vv[i].z * vv[i].z + vv[i].w * vv[i].w;
        }
        for (int off = 32; off > 0; off >>= 1) ss += __shfl_down(ss, off, 64);
        float nrm = sqrtf(__shfl(ss, 0, 64));
        float inv = 1.0f / fmaxf(nrm, 1e-12f);
#pragma unroll
        for (int i = 0; i < 4; ++i) {
            float a0 = vv[i].x * inv, a1 = vv[i].y * inv, a2 = vv[i].z * inv, a3 = vv[i].w * inv;
            ushort4 o;
            o.x = f2bf(a0); o.y = f2bf(a1); o.z = f2bf(a2); o.w = f2bf(a3);
            *(ushort4*)(xn + (size_t)row * D_MODEL + (lane + i * 64) * 4) = o;
            uchar4 o8;
            o8.x = f2e4m3(a0); o8.y = f2e4m3(a1); o8.z = f2e4m3(a2); o8.w = f2e4m3(a3);
            *(uchar4*)(xn8 + (size_t)row * D_MODEL + (lane + i * 64) * 4) = o8;
        }
        if (lane == 0) { norms[row] = nrm; cnt[row] = 0; }
    } else {
        size_t i = (size_t)(bid - NROWS / 4) * 256 + tid;   // float4 chunk index
        float4 w = ((const float4*)Wv)[i];
        ushort4 o;
        o.x = f2bf(w.x); o.y = f2bf(w.y); o.z = f2bf(w.z); o.w = f2bf(w.w);
        *(ushort4*)(Wvb + i * 4) = o;
    }
}

// ---------- L2: fused V-proj (bf16, blocks 0..1023) + symmetric sim (fp8, 1024..2079) ----------
__global__ __launch_bounds__(256) void k_main(const unsigned short* __restrict__ xn,
                                              const unsigned char* __restrict__ xn8,
                                              const unsigned short* __restrict__ Wvb,
                                              const float* __restrict__ bv,
                                              const float* __restrict__ norms,
                                              int* __restrict__ cnt,
                                              float* __restrict__ out) {
    __shared__ __align__(16) char smem[16384];
    int bid = blockIdx.x;
    int tid = threadIdx.x;
    int lane = tid & 63, wave = tid >> 6;
    int wm = wave & 1, wn = wave >> 1;
    int lrow = lane & 15, quad = lane >> 4;

    if (bid < VP_BLOCKS) {
        // ===== bf16 vproj: fragment-major LDS (16B lane-chunks), double-buffered =====
        short* As = (short*)smem;               // 2 x 2048 shorts
        short* Bs = (short*)(smem + 8192);      // 2 x 2048 shorts
        int rowBase = (bid >> 4) * TS;
        int colBase = (bid & 15) * TS;

        // stage one 64x32 bf16 tile: chunk c = tid -> frag group g=c>>6, lane l=c&63
        // global (row = g*16 + (l&15), k = (l>>4)*8 .. +8), LDS at c*16B  (R8-proven, 0 conflicts)
#define STAGE_BF16(src, rb, kk, dst)                                                    \
        { int l = tid & 63, g = tid >> 6;                                               \
          const unsigned short* ga = (src) + (size_t)((rb) + g * 16 + (l & 15)) * D_MODEL + (kk) + (l >> 4) * 8; \
          __builtin_amdgcn_global_load_lds(                                             \
              (const __attribute__((address_space(1))) unsigned int*)ga,                \
              (__attribute__((address_space(3))) unsigned int*)((dst) + tid * 8), 16, 0, 0); }

        f32x4 acc[2][2] = {};
        STAGE_BF16(xn, rowBase, 0, As);
        STAGE_BF16(Wvb, colBase, 0, Bs);
        __syncthreads();
        for (int it = 0; it < NIT; ++it) {
            int cur = it & 1, nxt = cur ^ 1;
            if (it + 1 < NIT) {
                STAGE_BF16(xn, rowBase, (it + 1) * BK, As + nxt * 2048);
                STAGE_BF16(Wvb, colBase, (it + 1) * BK, Bs + nxt * 2048);
            }
            const short* Ac = As + cur * 2048;
            const short* Bc = Bs + cur * 2048;
            bf16x8 av[2], bw[2];
#pragma unroll
            for (int mt = 0; mt < 2; ++mt)
                av[mt] = *(const bf16x8*)(Ac + ((wm * 2 + mt) * 64 + lane) * 8);
#pragma unroll
            for (int nt = 0; nt < 2; ++nt)
                bw[nt] = *(const bf16x8*)(Bc + ((wn * 2 + nt) * 64 + lane) * 8);
#pragma unroll
            for (int mt = 0; mt < 2; ++mt)
#pragma unroll
                for (int nt = 0; nt < 2; ++nt)
                    acc[mt][nt] = __builtin_amdgcn_mfma_f32_16x16x32_bf16(av[mt], bw[nt], acc[mt][nt], 0, 0, 0);
            __syncthreads();
        }
#pragma unroll
        for (int mt = 0; mt < 2; ++mt) {
#pragma unroll
            for (int nt = 0; nt < 2; ++nt) {
                int n = colBase + wn * 32 + nt * 16 + lrow;
                float bn = bv[n];
                int h = n >> 6, j = n & 63;
#pragma unroll
                for (int r = 0; r < 4; ++r) {
                    int m = rowBase + wm * 32 + mt * 16 + quad * 4 + r;
                    float val = acc[mt][nt][r] * norms[m] + bn;
                    int bb = m >> 11, s = m & (SEQ - 1);
                    out[(((size_t)(bb * NUM_HEADS + h)) * SEQ + s) * D_K + j] = val;
                }
            }
        }
    } else {
        // ===== fp8 sim: fragment-major (two 4B lane-regions per frag), double-buffered =====
        char* As = smem;                 // 2 x 2048 B
        char* Bs = smem + 4096;          // 2 x 2048 B
        int sidx = bid - VP_BLOCKS;
        int b = (sidx >= SIM_TRI) ? 1 : 0;
        int r0 = sidx - b * SIM_TRI;
        int bi = 0;
        while (r0 >= SIM_ROWB - bi) { r0 -= SIM_ROWB - bi; ++bi; }
        int bj = bi + r0;
        int rowBase = bi * TS;           // batch-local
        int colBase = bj * TS;
        const unsigned char* A8 = xn8 + (size_t)b * SEQ * D_MODEL;
        bool diag = (bi == bj);

        // stage one 64x32 fp8 tile (2KB): 8 regions of 256B; region r2 = g*2+w;
        // lane l holds global (row = g*16 + (l&15), kbyte = (l>>4)*8 + w*4 .. +4) at dst + r2*256 + l*4
#define STAGE_FP8(src, rb, kk, dst)                                                     \
        { _Pragma("unroll")                                                             \
          for (int p = 0; p < 2; ++p) {                                                 \
              int s0 = p * 256 + tid;                                                   \
              int l = s0 & 63, r2 = s0 >> 6;                                            \
              int g = r2 >> 1, w = r2 & 1;                                              \
              const unsigned char* ga = (src) + (size_t)((rb) + g * 16 + (l & 15)) * D_MODEL + (kk) + (l >> 4) * 8 + w * 4; \
              __builtin_amdgcn_global_load_lds(                                         \
                  (const __attribute__((address_space(1))) unsigned int*)ga,            \
                  (__attribute__((address_space(3))) unsigned int*)((dst) + s0 * 4), 4, 0, 0); } }

        f32x4 acc[2][2] = {};
        STAGE_FP8(A8, rowBase, 0, As);
        if (!diag) STAGE_FP8(A8, colBase, 0, Bs);
        __syncthreads();
        for (int it = 0; it < NIT; ++it) {
            int cur = it & 1, nxt = cur ^ 1;
            if (it + 1 < NIT) {
                STAGE_FP8(A8, rowBase, (it + 1) * BK, As + nxt * 2048);
                if (!diag) STAGE_FP8(A8, colBase, (it + 1) * BK, Bs + nxt * 2048);
            }
            const char* Ac = As + cur * 2048;
            const char* Bc = diag ? Ac : (Bs + cur * 2048);
            long long af[2], bf[2];
#pragma unroll
            for (int mt = 0; mt < 2; ++mt) {
                int g = wm * 2 + mt;
                unsigned int lo = *(const unsigned int*)(Ac + g * 512 + lane * 4);
                unsigned int hi = *(const unsigned int*)(Ac + g * 512 + 256 + lane * 4);
                af[mt] = (long long)(((unsigned long long)hi << 32) | lo);
            }
#pragma unroll
            for (int nt = 0; nt < 2; ++nt) {
                int g = wn * 2 + nt;
                unsigned int lo = *(const unsigned int*)(Bc + g * 512 + lane * 4);
                unsigned int hi = *(const unsigned int*)(Bc + g * 512 + 256 + lane * 4);
                bf[nt] = (long long)(((unsigned long long)hi << 32) | lo);
            }
#pragma unroll
            for (int mt = 0; mt < 2; ++mt)
#pragma unroll
                for (int nt = 0; nt < 2; ++nt)
                    acc[mt][nt] = __builtin_amdgcn_mfma_f32_16x16x32_fp8_fp8(af[mt], bf[nt], acc[mt][nt], 0, 0, 0);
            __syncthreads();
        }
        int* cb = cnt + b * SEQ;
#pragma unroll
        for (int mt = 0; mt < 2; ++mt) {
#pragma unroll
            for (int nt = 0; nt < 2; ++nt) {
                int n = colBase + wn * 32 + nt * 16 + lrow;
#pragma unroll
                for (int r = 0; r < 4; ++r) {
                    int m = rowBase + wm * 32 + mt * 16 + quad * 4 + r;
                    if (acc[mt][nt][r] > SIM_THRESH) {
                        atomicAdd(&cb[m], 1);
                        if (!diag) atomicAdd(&cb[n], 1);
                    }
                }
            }
        }
    }
}

// ---------- L3: fix rows with cnt != 1 (cold; cnt==1 rows already hold out = v row).
// Self-sufficient: recomputes mask row (bf16, exact pipeline), q/k/v rows on demand. ----------
__global__ __launch_bounds__(256) void k_fix(
    const float* __restrict__ x,
    const float* __restrict__ Wq, const float* __restrict__ bq,
    const float* __restrict__ Wk, const float* __restrict__ bk,
    const unsigned short* __restrict__ Wvb, const float* __restrict__ bvv,
    const unsigned short* __restrict__ xn,
    const float* __restrict__ norms,
    const int* __restrict__ cnt,
    float* __restrict__ out)
{
    int tid = threadIdx.x;
    int rowBase = blockIdx.x * 256;

    __shared__ int list[256];
    __shared__ int nlist;
    if (tid == 0) nlist = 0;
    __syncthreads();
    int grow = rowBase + tid;
    if (cnt[grow] != 1) { int p = atomicAdd(&nlist, 1); list[p] = grow; }
    __syncthreads();
    int nfix = nlist;
    if (nfix == 0) return;

    __shared__ uint8_t mrow[SEQ];
    __shared__ float q_row[D_MODEL];
    __shared__ float k_row[D_MODEL];
    __shared__ float v_row[D_MODEL];
    __shared__ float accO[D_MODEL];
    __shared__ float m_h[NUM_HEADS], l_h[NUM_HEADS], alpha_h[NUM_HEADS], p_h[NUM_HEADS];

    for (int li = 0; li < nfix; ++li) {
        int row = list[li];
        int b = row >> 11, s = row & (SEQ - 1);

        const unsigned short* xs = xn + (size_t)row * D_MODEL;
        for (int t = tid; t < SEQ; t += 256) {
            const unsigned short* xt = xn + ((size_t)b * SEQ + t) * D_MODEL;
            float d = 0.f;
            for (int k = 0; k < D_MODEL; ++k) d += bf2f(xs[k]) * bf2f(xt[k]);
            mrow[t] = (d > SIM_THRESH) ? 1 : 0;
        }

        const float* xrow = x + (size_t)row * D_MODEL;
        for (int c = tid; c < D_MODEL; c += 256) {
            const float* w = Wq + (size_t)c * D_MODEL;
            float acc = bq[c];
            for (int d = 0; d < D_MODEL; ++d) acc += xrow[d] * w[d];
            q_row[c] = acc;
            accO[c] = 0.f;
        }
        if (tid < NUM_HEADS) { m_h[tid] = -INFINITY; l_h[tid] = 0.f; }
        __syncthreads();

        for (int t = 0; t < SEQ; ++t) {
            if (!mrow[t]) continue;
            const float* xt = x + ((size_t)b * SEQ + t) * D_MODEL;
            const unsigned short* xnt = xn + ((size_t)b * SEQ + t) * D_MODEL;
            float nt = norms[b * SEQ + t];
            for (int c = tid; c < D_MODEL; c += 256) {
                const float* w = Wk + (size_t)c * D_MODEL;
                float acc = bk[c];
                for (int d = 0; d < D_MODEL; ++d) acc += xt[d] * w[d];
                k_row[c] = acc;
                const unsigned short* wv = Wvb + (size_t)c * D_MODEL;
                float av = 0.f;
                for (int d = 0; d < D_MODEL; ++d) av += bf2f(xnt[d]) * bf2f(wv[d]);
                v_row[c] = av * nt + bvv[c];
            }
            __syncthreads();
            if (tid < NUM_HEADS) {
                float sc = 0.f;
                for (int j = 0; j < D_K; ++j) sc += q_row[tid * D_K + j] * k_row[tid * D_K + j];
                sc *= 0.125f;
                float mnew = fmaxf(m_h[tid], sc);
                float alpha = expf(m_h[tid] - mnew);
                float p = expf(sc - mnew);
                l_h[tid] = l_h[tid] * alpha + p;
                m_h[tid] = mnew;
                alpha_h[tid] = alpha;
                p_h[tid] = p;
            }
            __syncthreads();
            for (int c = tid; c < D_MODEL; c += 256) {
                int h = c >> 6;
                accO[c] = accO[c] * alpha_h[h] + p_h[h] * v_row[c];
            }
            __syncthreads();
        }
        for (int c = tid; c < D_MODEL; c += 256) {
            int h = c >> 6, j = c & 63;
            out[(((size_t)(b * NUM_HEADS + h)) * SEQ + s) * D_K + j] = accO[c] / l_h[h];
        }
        __syncthreads();
    }
}

extern "C" void kernel_launch(void* const* d_in, const int* in_sizes, int n_in,
                              void* d_out, int out_size, void* d_ws, size_t ws_size,
                              hipStream_t stream) {
    const float* x  = (const float*)d_in[0];
    const float* Wq = (const float*)d_in[1];
    const float* bq = (const float*)d_in[2];
    const float* Wk = (const float*)d_in[3];
    const float* bk = (const float*)d_in[4];
    const float* Wv = (const float*)d_in[5];
    const float* bv = (const float*)d_in[6];
    float* out = (float*)d_out;

    // workspace: xn bf16 (8MB) | Wvb bf16 (2MB) | xn8 fp8 (4MB) | norms (16KB) | cnt (16KB)
    unsigned short* xn  = (unsigned short*)d_ws;
    unsigned short* Wvb = xn + (size_t)NROWS * D_MODEL;
    unsigned char* xn8  = (unsigned char*)(Wvb + (size_t)D_MODEL * D_MODEL);
    float* norms = (float*)(xn8 + (size_t)NROWS * D_MODEL);
    int* cnt     = (int*)(norms + NROWS);

    // L1: 1024 row-blocks (wave-per-row) + 1024 Wv-cast blocks
    k_prep<<<NROWS / 4 + D_MODEL * D_MODEL / 1024, 256, 0, stream>>>(x, Wv, xn, xn8, Wvb, norms, cnt);

    // L2: 1024 bf16 vproj blocks + 1056 fp8 sim blocks
    k_main<<<GRID, 256, 0, stream>>>(xn, xn8, Wvb, bv, norms, cnt, out);

    // L3: fix non-singleton rows (cold)
    k_fix<<<NROWS / 256, 256, 0, stream>>>(x, Wq, bq, Wk, bk, Wvb, bv, xn, norms, cnt, out);
}

// Round 10
// 132.839 us; speedup vs baseline: 1.4299x; 1.4299x over previous
//
#include <hip/hip_runtime.h>
#include <stdint.h>
#include <math.h>

#define D_MODEL 1024
#define NUM_HEADS 16
#define D_K 64
#define SEQ 2048
#define BATCH 2
#define SIM_THRESH 0.7f
#define THRESH_I8 6451            // 0.4 * 127^2 : conservative screen threshold

#define BK 32                     // K chunk (elements) per barrier
#define NIT (D_MODEL / BK)        // 32

#define NROWS (BATCH * SEQ)                         // 4096
#define VPT 128                                     // vproj tile
#define VP_BLOCKS ((NROWS / VPT) * (D_MODEL / VPT)) // 32*8 = 256
#define STS 64                                      // sim tile
#define SIM_ROWB (SEQ / STS)                        // 32
#define SIM_TRI (SIM_ROWB * (SIM_ROWB + 1) / 2)     // 528
#define SIM_BLOCKS (SIM_TRI * BATCH)                // 1056
#define GRID (VP_BLOCKS + SIM_BLOCKS)               // 1312

typedef __attribute__((ext_vector_type(8))) short bf16x8;
typedef __attribute__((ext_vector_type(4))) float f32x4;
typedef __attribute__((ext_vector_type(4))) int i32x4;

static __device__ __forceinline__ unsigned short f2bf(float f) {
    unsigned int u = __float_as_uint(f);
    unsigned int r = (u + 0x7FFF + ((u >> 16) & 1)) >> 16;   // RNE
    return (unsigned short)r;
}
static __device__ __forceinline__ float bf2f(unsigned short u) {
    return __uint_as_float(((unsigned int)u) << 16);
}

// ---------- L1: normalize x rows -> bf16 + i8 (+norms, cnt=1); cast Wv -> bf16 ----------
__global__ __launch_bounds__(256) void k_prep(const float* __restrict__ x,
                                              const float* __restrict__ Wv,
                                              unsigned short* __restrict__ xn,
                                              signed char* __restrict__ xq,
                                              unsigned short* __restrict__ Wvb,
                                              float* __restrict__ norms,
                                              int* __restrict__ cnt) {
    int bid = blockIdx.x, tid = threadIdx.x;
    int lane = tid & 63, wv = tid >> 6;
    if (bid < NROWS / 4) {
        int row = bid * 4 + wv;
        const float4* xr = (const float4*)(x + (size_t)row * D_MODEL);
        float4 vv[4];
        float ss = 0.f;
#pragma unroll
        for (int i = 0; i < 4; ++i) {
            vv[i] = xr[lane + i * 64];
            ss += vv[i].x * vv[i].x + vv[i].y * vv[i].y + vv[i].z * vv[i].z + vv[i].w * vv[i].w;
        }
        for (int off = 32; off > 0; off >>= 1) ss += __shfl_down(ss, off, 64);
        float nrm = sqrtf(__shfl(ss, 0, 64));
        float inv = 1.0f / fmaxf(nrm, 1e-12f);
#pragma unroll
        for (int i = 0; i < 4; ++i) {
            float a0 = vv[i].x * inv, a1 = vv[i].y * inv, a2 = vv[i].z * inv, a3 = vv[i].w * inv;
            ushort4 o;
            o.x = f2bf(a0); o.y = f2bf(a1); o.z = f2bf(a2); o.w = f2bf(a3);
            *(ushort4*)(xn + (size_t)row * D_MODEL + (lane + i * 64) * 4) = o;
            char4 q;
            q.x = (signed char)(int)rintf(a0 * 127.f);
            q.y = (signed char)(int)rintf(a1 * 127.f);
            q.z = (signed char)(int)rintf(a2 * 127.f);
            q.w = (signed char)(int)rintf(a3 * 127.f);
            *(char4*)(xq + (size_t)row * D_MODEL + (lane + i * 64) * 4) = q;
        }
        if (lane == 0) { norms[row] = nrm; cnt[row] = 1; }   // diagonal pre-counted (cos=1 exactly)
    } else {
        size_t i = (size_t)(bid - NROWS / 4) * 256 + tid;    // float4 chunk index
        float4 w = ((const float4*)Wv)[i];
        ushort4 o;
        o.x = f2bf(w.x); o.y = f2bf(w.y); o.z = f2bf(w.z); o.w = f2bf(w.w);
        *(ushort4*)(Wvb + i * 4) = o;
    }
}

// ---------- L2: fused vproj (bf16 128x128, blocks 0..255) + sim screen (i8 64x64, 256..1311) ----
__global__ __launch_bounds__(256) void k_main(const unsigned short* __restrict__ xn,
                                              const signed char* __restrict__ xq,
                                              const unsigned short* __restrict__ Wvb,
                                              const float* __restrict__ bv,
                                              const float* __restrict__ norms,
                                              int* __restrict__ cnt,
                                              float* __restrict__ out) {
    __shared__ __align__(16) char smem[16384];
    int bid = blockIdx.x;
    int tid = threadIdx.x;
    int lane = tid & 63, wave = tid >> 6;
    int wm = wave & 1, wn = wave >> 1;
    int lrow = lane & 15, quad = lane >> 4;

    if (bid < VP_BLOCKS) {
        // ===== bf16 vproj, 128x128 tile, BK=32, single-buffered (R3-proven layout) =====
        short* As = (short*)smem;             // 128x32 = 8KB
        short* Bs = (short*)(smem + 8192);    // 128x32 = 8KB
        int rowBase = (bid >> 3) * VPT;
        int colBase = (bid & 7) * VPT;

        int aoff[4], boff[4];
#pragma unroll
        for (int i = 0; i < 4; ++i) {
            aoff[i] = (wm * 64 + i * 16 + lrow) * BK + quad * 8;
            boff[i] = (wn * 64 + i * 16 + lrow) * BK + quad * 8;
        }
        f32x4 acc[4][4] = {};
        for (int kk = 0; kk < D_MODEL; kk += BK) {
#pragma unroll
            for (int p = 0; p < 2; ++p) {     // stage A: 128x32 bf16, 16B/lane coalesced
                int idx = p * 256 + tid;
                int row = idx >> 2, ch = idx & 3;
                const unsigned short* ga = xn + (size_t)(rowBase + row) * D_MODEL + kk + ch * 8;
                __builtin_amdgcn_global_load_lds(
                    (const __attribute__((address_space(1))) unsigned int*)ga,
                    (__attribute__((address_space(3))) unsigned int*)(As + idx * 8), 16, 0, 0);
            }
#pragma unroll
            for (int p = 0; p < 2; ++p) {     // stage B
                int idx = p * 256 + tid;
                int row = idx >> 2, ch = idx & 3;
                const unsigned short* ga = Wvb + (size_t)(colBase + row) * D_MODEL + kk + ch * 8;
                __builtin_amdgcn_global_load_lds(
                    (const __attribute__((address_space(1))) unsigned int*)ga,
                    (__attribute__((address_space(3))) unsigned int*)(Bs + idx * 8), 16, 0, 0);
            }
            __syncthreads();
            bf16x8 av[4], bw[4];
#pragma unroll
            for (int i = 0; i < 4; ++i) av[i] = *(const bf16x8*)(As + aoff[i]);
#pragma unroll
            for (int i = 0; i < 4; ++i) bw[i] = *(const bf16x8*)(Bs + boff[i]);
#pragma unroll
            for (int mt = 0; mt < 4; ++mt)
#pragma unroll
                for (int nt = 0; nt < 4; ++nt)
                    acc[mt][nt] = __builtin_amdgcn_mfma_f32_16x16x32_bf16(av[mt], bw[nt], acc[mt][nt], 0, 0, 0);
            __syncthreads();
        }
#pragma unroll
        for (int mt = 0; mt < 4; ++mt) {
#pragma unroll
            for (int nt = 0; nt < 4; ++nt) {
                int n = colBase + wn * 64 + nt * 16 + lrow;
                float bn = bv[n];
                int h = n >> 6, j = n & 63;
#pragma unroll
                for (int r = 0; r < 4; ++r) {
                    int m = rowBase + wm * 64 + mt * 16 + quad * 4 + r;
                    float val = acc[mt][nt][r] * norms[m] + bn;
                    int bb = m >> 11, s = m & (SEQ - 1);
                    out[(((size_t)(bb * NUM_HEADS + h)) * SEQ + s) * D_K + j] = val;
                }
            }
        }
    } else {
        // ===== i8 sim screen, 64x64 tile, BK=32, exact int32 dots =====
        char* As = smem;                 // 64x32 i8 = 2KB
        char* Bs = smem + 2048;          // 64x32 i8 = 2KB
        int sidx = bid - VP_BLOCKS;
        int b = (sidx >= SIM_TRI) ? 1 : 0;
        int r0 = sidx - b * SIM_TRI;
        int bi = 0;
        while (r0 >= SIM_ROWB - bi) { r0 -= SIM_ROWB - bi; ++bi; }
        int bj = bi + r0;
        int rowBase = bi * STS;          // batch-local
        int colBase = bj * STS;
        const signed char* A8 = xq + (size_t)b * SEQ * D_MODEL;
        bool diag = (bi == bj);
        const char* Bsp = diag ? As : Bs;

        i32x4 acc[2][2] = {};
        for (int kk = 0; kk < D_MODEL; kk += BK) {
            // waves 0-1 stage A (2KB), waves 2-3 stage B (2KB); 16B/lane, 32B runs
            int t = tid & 127;
            int row = t >> 1, half = t & 1;
            if (tid < 128) {
                const signed char* ga = A8 + (size_t)(rowBase + row) * D_MODEL + kk + half * 16;
                __builtin_amdgcn_global_load_lds(
                    (const __attribute__((address_space(1))) unsigned int*)ga,
                    (__attribute__((address_space(3))) unsigned int*)(As + t * 16), 16, 0, 0);
            } else if (!diag) {
                const signed char* ga = A8 + (size_t)(colBase + row) * D_MODEL + kk + half * 16;
                __builtin_amdgcn_global_load_lds(
                    (const __attribute__((address_space(1))) unsigned int*)ga,
                    (__attribute__((address_space(3))) unsigned int*)(Bs + t * 16), 16, 0, 0);
            }
            __syncthreads();
            long long af[2], bf[2];
#pragma unroll
            for (int mt = 0; mt < 2; ++mt)
                af[mt] = *(const long long*)(As + (wm * 32 + mt * 16 + lrow) * 32 + quad * 8);
#pragma unroll
            for (int nt = 0; nt < 2; ++nt)
                bf[nt] = *(const long long*)(Bsp + (wn * 32 + nt * 16 + lrow) * 32 + quad * 8);
#pragma unroll
            for (int mt = 0; mt < 2; ++mt)
#pragma unroll
                for (int nt = 0; nt < 2; ++nt)
                    acc[mt][nt] = __builtin_amdgcn_mfma_i32_16x16x32_i8(af[mt], bf[nt], acc[mt][nt], 0, 0, 0);
            __syncthreads();
        }
        int* cb = cnt + b * SEQ;
#pragma unroll
        for (int mt = 0; mt < 2; ++mt) {
#pragma unroll
            for (int nt = 0; nt < 2; ++nt) {
                int n = colBase + wn * 32 + nt * 16 + lrow;
#pragma unroll
                for (int r = 0; r < 4; ++r) {
                    int m = rowBase + wm * 32 + mt * 16 + quad * 4 + r;
                    if (acc[mt][nt][r] > THRESH_I8 && m != n) {
                        atomicAdd(&cb[m], 1);
                        if (!diag) atomicAdd(&cb[n], 1);
                    }
                }
            }
        }
    }
}

// ---------- L3: rows with cnt != 1: recompute EXACT bf16 count; if ==1 the out row is
// already correct (v row); else full online-softmax attention (cold). ----------
__global__ __launch_bounds__(256) void k_fix(
    const float* __restrict__ x,
    const float* __restrict__ Wq, const float* __restrict__ bq,
    const float* __restrict__ Wk, const float* __restrict__ bk,
    const unsigned short* __restrict__ Wvb, const float* __restrict__ bvv,
    const unsigned short* __restrict__ xn,
    const float* __restrict__ norms,
    const int* __restrict__ cnt,
    float* __restrict__ out)
{
    int tid = threadIdx.x;
    int rowBase = blockIdx.x * 256;

    __shared__ int list[256];
    __shared__ int nlist;
    if (tid == 0) nlist = 0;
    __syncthreads();
    int grow = rowBase + tid;
    if (cnt[grow] != 1) { int p = atomicAdd(&nlist, 1); list[p] = grow; }
    __syncthreads();
    int nfix = nlist;
    if (nfix == 0) return;

    __shared__ uint8_t mrow[SEQ];
    __shared__ int exact_sh;
    __shared__ float q_row[D_MODEL];
    __shared__ float k_row[D_MODEL];
    __shared__ float v_row[D_MODEL];
    __shared__ float accO[D_MODEL];
    __shared__ float m_h[NUM_HEADS], l_h[NUM_HEADS], alpha_h[NUM_HEADS], p_h[NUM_HEADS];

    for (int li = 0; li < nfix; ++li) {
        int row = list[li];
        int b = row >> 11, s = row & (SEQ - 1);

        if (tid == 0) exact_sh = 0;
        __syncthreads();
        const unsigned short* xs = xn + (size_t)row * D_MODEL;
        int myc = 0;
        for (int t = tid; t < SEQ; t += 256) {
            const unsigned short* xt = xn + ((size_t)b * SEQ + t) * D_MODEL;
            float d = 0.f;
            for (int k = 0; k < D_MODEL; ++k) d += bf2f(xs[k]) * bf2f(xt[k]);
            uint8_t mk = (d > SIM_THRESH) ? 1 : 0;
            mrow[t] = mk;
            myc += mk;
        }
        atomicAdd(&exact_sh, myc);
        __syncthreads();
        if (exact_sh == 1) { __syncthreads(); continue; }   // screen false-positive: out already = v row

        const float* xrow = x + (size_t)row * D_MODEL;
        for (int c = tid; c < D_MODEL; c += 256) {
            const float* w = Wq + (size_t)c * D_MODEL;
            float acc = bq[c];
            for (int d = 0; d < D_MODEL; ++d) acc += xrow[d] * w[d];
            q_row[c] = acc;
            accO[c] = 0.f;
        }
        if (tid < NUM_HEADS) { m_h[tid] = -INFINITY; l_h[tid] = 0.f; }
        __syncthreads();

        for (int t = 0; t < SEQ; ++t) {
            if (!mrow[t]) continue;
            const float* xt = x + ((size_t)b * SEQ + t) * D_MODEL;
            const unsigned short* xnt = xn + ((size_t)b * SEQ + t) * D_MODEL;
            float nt = norms[b * SEQ + t];
            for (int c = tid; c < D_MODEL; c += 256) {
                const float* w = Wk + (size_t)c * D_MODEL;
                float acc = bk[c];
                for (int d = 0; d < D_MODEL; ++d) acc += xt[d] * w[d];
                k_row[c] = acc;
                const unsigned short* wv = Wvb + (size_t)c * D_MODEL;
                float av = 0.f;
                for (int d = 0; d < D_MODEL; ++d) av += bf2f(xnt[d]) * bf2f(wv[d]);
                v_row[c] = av * nt + bvv[c];
            }
            __syncthreads();
            if (tid < NUM_HEADS) {
                float sc = 0.f;
                for (int j = 0; j < D_K; ++j) sc += q_row[tid * D_K + j] * k_row[tid * D_K + j];
                sc *= 0.125f;
                float mnew = fmaxf(m_h[tid], sc);
                float alpha = expf(m_h[tid] - mnew);
                float p = expf(sc - mnew);
                l_h[tid] = l_h[tid] * alpha + p;
                m_h[tid] = mnew;
                alpha_h[tid] = alpha;
                p_h[tid] = p;
            }
            __syncthreads();
            for (int c = tid; c < D_MODEL; c += 256) {
                int h = c >> 6;
                accO[c] = accO[c] * alpha_h[h] + p_h[h] * v_row[c];
            }
            __syncthreads();
        }
        for (int c = tid; c < D_MODEL; c += 256) {
            int h = c >> 6, j = c & 63;
            out[(((size_t)(b * NUM_HEADS + h)) * SEQ + s) * D_K + j] = accO[c] / l_h[h];
        }
        __syncthreads();
    }
}

extern "C" void kernel_launch(void* const* d_in, const int* in_sizes, int n_in,
                              void* d_out, int out_size, void* d_ws, size_t ws_size,
                              hipStream_t stream) {
    const float* x  = (const float*)d_in[0];
    const float* Wq = (const float*)d_in[1];
    const float* bq = (const float*)d_in[2];
    const float* Wk = (const float*)d_in[3];
    const float* bk = (const float*)d_in[4];
    const float* Wv = (const float*)d_in[5];
    const float* bv = (const float*)d_in[6];
    float* out = (float*)d_out;

    // workspace: xn bf16 (8MB) | Wvb bf16 (2MB) | xq i8 (4MB) | norms (16KB) | cnt (16KB)
    unsigned short* xn  = (unsigned short*)d_ws;
    unsigned short* Wvb = xn + (size_t)NROWS * D_MODEL;
    signed char* xq     = (signed char*)(Wvb + (size_t)D_MODEL * D_MODEL);
    float* norms = (float*)(xq + (size_t)NROWS * D_MODEL);
    int* cnt     = (int*)(norms + NROWS);

    // L1: 1024 row-blocks (wave-per-row) + 1024 Wv-cast blocks
    k_prep<<<NROWS / 4 + D_MODEL * D_MODEL / 1024, 256, 0, stream>>>(x, Wv, xn, xq, Wvb, norms, cnt);

    // L2: 256 bf16 vproj blocks (128x128) + 1056 i8 sim blocks (64x64)
    k_main<<<GRID, 256, 0, stream>>>(xn, xq, Wvb, bv, norms, cnt, out);

    // L3: exact recheck + attention for flagged rows (cold)
    k_fix<<<NROWS / 256, 256, 0, stream>>>(x, Wq, bq, Wk, bk, Wvb, bv, xn, norms, cnt, out);
}